// Round 3
// baseline (651.947 us; speedup 1.0000x reference)
//
#include <hip/hip_runtime.h>
#include <hip/hip_bf16.h>

// Problem constants
#define T_TOK 128
#define N_EXP 8
#define HID   1024
#define INTER 4096

typedef __bf16 bf16x8 __attribute__((ext_vector_type(8)));
typedef __bf16 bf16x4 __attribute__((ext_vector_type(4)));
typedef float  f32x4  __attribute__((ext_vector_type(4)));

#define MFMA16(A, B, C) __builtin_amdgcn_mfma_f32_16x16x32_bf16(A, B, C, 0, 0, 0)

// ---------------------------------------------------------------------------
// Kernel 1: routing. softmax over 8 logits -> top2 -> renormalized scales.
// ---------------------------------------------------------------------------
__global__ void route_kernel(const float* __restrict__ routing,
                             int* __restrict__ cnt,
                             int* __restrict__ tok,
                             float* __restrict__ scal) {
    int t = threadIdx.x;            // token id 0..127
    int wave = t >> 6, lane = t & 63;

    float l[N_EXP];
#pragma unroll
    for (int e = 0; e < N_EXP; ++e) l[e] = routing[t * N_EXP + e];

    int i1 = 0; float v1 = l[0];
#pragma unroll
    for (int e = 1; e < N_EXP; ++e) if (l[e] > v1) { v1 = l[e]; i1 = e; }
    int i2 = -1; float v2 = -1e30f;
#pragma unroll
    for (int e = 0; e < N_EXP; ++e) if (e != i1 && l[e] > v2) { v2 = l[e]; i2 = e; }

    float s1 = 1.0f / (1.0f + __expf(v2 - v1));
    float s2 = 1.0f - s1;

    __shared__ unsigned long long wmask[2][N_EXP];
#pragma unroll
    for (int e = 0; e < N_EXP; ++e) {
        bool sel = (i1 == e) || (i2 == e);
        unsigned long long m = __ballot(sel);
        if (lane == 0) wmask[wave][e] = m;
    }
    __syncthreads();
#pragma unroll
    for (int e = 0; e < N_EXP; ++e) {
        bool sel = (i1 == e) || (i2 == e);
        unsigned long long m = __ballot(sel);
        int pre  = __popcll(m & ((1ull << lane) - 1ull));
        int base = (wave == 1) ? __popcll(wmask[0][e]) : 0;
        if (sel) {
            int slot = base + pre;
            tok [e * T_TOK + slot] = t;
            scal[e * T_TOK + slot] = (i1 == e) ? s1 : s2;
        }
        if (t == 0) cnt[e] = __popcll(wmask[0][e]) + __popcll(wmask[1][e]);
    }
}

// ---------------------------------------------------------------------------
// Kernel 2: gather routed hidden rows into compact bf16 A-buffer.
// ---------------------------------------------------------------------------
__global__ void prep_kernel(const float* __restrict__ hidden,
                            const int* __restrict__ cnt,
                            const int* __restrict__ tok,
                            __bf16* __restrict__ abuf) {
    int b = blockIdx.x;
    int e = b >> 7, s = b & 127;
    if (s >= cnt[e]) return;
    int t = tok[e * T_TOK + s];
    const float4* src = (const float4*)(hidden + (size_t)t * HID);
    __bf16* dst = abuf + ((size_t)e * T_TOK + s) * HID;
#pragma unroll
    for (int it = 0; it < 4; ++it) {
        int idx = it * 64 + threadIdx.x;
        float4 v = src[idx];
        bf16x4 pk;
        pk[0] = (__bf16)v.x; pk[1] = (__bf16)v.y;
        pk[2] = (__bf16)v.z; pk[3] = (__bf16)v.w;
        *(bf16x4*)(dst + idx * 4) = pk;
    }
}

__device__ __forceinline__ bf16x8 cvt8(float4 a, float4 b) {
    bf16x8 r;
    r[0] = (__bf16)a.x; r[1] = (__bf16)a.y; r[2] = (__bf16)a.z; r[3] = (__bf16)a.w;
    r[4] = (__bf16)b.x; r[5] = (__bf16)b.y; r[6] = (__bf16)b.z; r[7] = (__bf16)b.w;
    return r;
}

// ---------------------------------------------------------------------------
// Kernel 3: GEMM1 + swiglu. m-dimension in the grid (4 layers x 32 tokens),
// MG<=2 templated end-to-end -> low VGPR, UF=4 deep-unrolled branch-free
// k-loop with 16 outstanding dwordx4 per wave.
// ---------------------------------------------------------------------------
template<int MG>
__device__ __forceinline__ void g1_body(const float* __restrict__ bl,
                                        const float* __restrict__ bg,
                                        const __bf16* __restrict__ ap,
                                        __bf16* __restrict__ act,
                                        int e, int n0, int lr, int lq,
                                        int slot_base, int c) {
    constexpr int UF = 4;
    f32x4 accl[MG], accg[MG];
#pragma unroll
    for (int m = 0; m < MG; ++m) {
        accl[m] = (f32x4){0.f, 0.f, 0.f, 0.f};
        accg[m] = (f32x4){0.f, 0.f, 0.f, 0.f};
    }

    for (int k0 = 0; k0 < HID; k0 += 32 * UF) {
        float4 WL[UF][2], WG[UF][2];
        bf16x8 A[UF][MG];
#pragma unroll
        for (int u = 0; u < UF; ++u) {
            WL[u][0] = *(const float4*)(bl + k0 + u * 32);
            WL[u][1] = *(const float4*)(bl + k0 + u * 32 + 4);
            WG[u][0] = *(const float4*)(bg + k0 + u * 32);
            WG[u][1] = *(const float4*)(bg + k0 + u * 32 + 4);
        }
#pragma unroll
        for (int u = 0; u < UF; ++u)
#pragma unroll
            for (int m = 0; m < MG; ++m)
                A[u][m] = *(const bf16x8*)(ap + (size_t)m * 16 * HID + k0 + u * 32);
#pragma unroll
        for (int u = 0; u < UF; ++u) {
            bf16x8 BL = cvt8(WL[u][0], WL[u][1]);
            bf16x8 BG = cvt8(WG[u][0], WG[u][1]);
#pragma unroll
            for (int m = 0; m < MG; ++m) {
                accl[m] = MFMA16(A[u][m], BL, accl[m]);
                accg[m] = MFMA16(A[u][m], BG, accg[m]);
            }
        }
    }

#pragma unroll
    for (int m = 0; m < MG; ++m) {
#pragma unroll
        for (int r = 0; r < 4; ++r) {
            int slot = slot_base + m * 16 + lq * 4 + r;
            if (slot < c) {
                float lin  = accl[m][r];
                float gate = accg[m][r];
                float a = lin * (1.0f / (1.0f + __expf(-lin))) * gate;
                act[((size_t)e * T_TOK + slot) * INTER + n0 + lr] = (__bf16)a;
            }
        }
    }
}

__global__ __launch_bounds__(256) void gemm1_kernel(
    const float* __restrict__ w1,
    const int* __restrict__ cnt,
    const __bf16* __restrict__ abuf,
    __bf16* __restrict__ act) {
    int bx  = blockIdx.x;                 // e(3) | nb(6) | mg2(2)
    int mg2 = bx & 3, nb = (bx >> 2) & 63, e = bx >> 8;
    int c   = cnt[e];
    int rem = c - mg2 * 32;
    if (rem <= 0) return;

    int wave = threadIdx.x >> 6, lane = threadIdx.x & 63;
    int n0 = nb * 64 + wave * 16;
    int lr = lane & 15, lq = lane >> 4;
    int slot_base = mg2 * 32;

    const float* bl = w1 + ((size_t)e * 2 * INTER + n0 + lr) * HID + lq * 8;
    const float* bg = bl + (size_t)INTER * HID;
    const __bf16* ap = abuf + ((size_t)e * T_TOK + slot_base + lr) * HID + lq * 8;

    if (rem > 16) g1_body<2>(bl, bg, ap, act, e, n0, lr, lq, slot_base, c);
    else          g1_body<1>(bl, bg, ap, act, e, n0, lr, lq, slot_base, c);
}

// ---------------------------------------------------------------------------
// Kernel 4: GEMM2 + scaled scatter-add. K-split 4, m-layers in grid, MG<=2.
// ---------------------------------------------------------------------------
#define KSPLIT 4
#define KCH (INTER / KSPLIT)   // 1024

template<int MG>
__device__ __forceinline__ void g2_body(const float* __restrict__ bp,
                                        const __bf16* __restrict__ ap,
                                        const int* __restrict__ tok,
                                        const float* __restrict__ scal,
                                        float* __restrict__ out,
                                        int e, int n0, int lr, int lq,
                                        int slot_base, int c) {
    constexpr int UF = 4;
    f32x4 acc[MG];
#pragma unroll
    for (int m = 0; m < MG; ++m) acc[m] = (f32x4){0.f, 0.f, 0.f, 0.f};

    for (int k0 = 0; k0 < KCH; k0 += 32 * UF) {
        float4 W[UF][2];
        bf16x8 A[UF][MG];
#pragma unroll
        for (int u = 0; u < UF; ++u) {
            W[u][0] = *(const float4*)(bp + k0 + u * 32);
            W[u][1] = *(const float4*)(bp + k0 + u * 32 + 4);
        }
#pragma unroll
        for (int u = 0; u < UF; ++u)
#pragma unroll
            for (int m = 0; m < MG; ++m)
                A[u][m] = *(const bf16x8*)(ap + (size_t)m * 16 * INTER + k0 + u * 32);
#pragma unroll
        for (int u = 0; u < UF; ++u) {
            bf16x8 B = cvt8(W[u][0], W[u][1]);
#pragma unroll
            for (int m = 0; m < MG; ++m)
                acc[m] = MFMA16(A[u][m], B, acc[m]);
        }
    }

#pragma unroll
    for (int m = 0; m < MG; ++m) {
#pragma unroll
        for (int r = 0; r < 4; ++r) {
            int slot = slot_base + m * 16 + lq * 4 + r;
            if (slot < c) {
                int   t    = tok [e * T_TOK + slot];
                float coef = scal[e * T_TOK + slot];
                atomicAdd(&out[(size_t)t * HID + n0 + lr], coef * acc[m][r]);
            }
        }
    }
}

__global__ __launch_bounds__(256) void gemm2_kernel(
    const float* __restrict__ w2,
    const int* __restrict__ cnt,
    const int* __restrict__ tok,
    const float* __restrict__ scal,
    const __bf16* __restrict__ act,
    float* __restrict__ out) {
    int bx  = blockIdx.x;                 // e(3) | nb(4) | ks(2) | mg2(2)
    int mg2 = bx & 3, ks = (bx >> 2) & (KSPLIT - 1), nb = (bx >> 4) & 15, e = bx >> 8;
    int c   = cnt[e];
    int rem = c - mg2 * 32;
    if (rem <= 0) return;

    int wave = threadIdx.x >> 6, lane = threadIdx.x & 63;
    int n0 = nb * 64 + wave * 16;
    int lr = lane & 15, lq = lane >> 4;
    int slot_base = mg2 * 32;

    const float* bp = w2 + ((size_t)e * HID + n0 + lr) * INTER + ks * KCH + lq * 8;
    const __bf16* ap = act + ((size_t)e * T_TOK + slot_base + lr) * INTER + ks * KCH + lq * 8;

    if (rem > 16) g2_body<2>(bp, ap, tok, scal, out, e, n0, lr, lq, slot_base, c);
    else          g2_body<1>(bp, ap, tok, scal, out, e, n0, lr, lq, slot_base, c);
}

// ---------------------------------------------------------------------------
// Workspace layout (bytes):
//   [0,32)            cnt[8]
//   [64, 64+4096)     tok_list[8][128]
//   [4160, 8256)      tok_scale[8][128]
//   [16384, +2MB)     abuf  bf16 [8][128][1024]
//   [16384+2MB, +8MB) act   bf16 [8][128][4096]
// ---------------------------------------------------------------------------
extern "C" void kernel_launch(void* const* d_in, const int* in_sizes, int n_in,
                              void* d_out, int out_size, void* d_ws, size_t ws_size,
                              hipStream_t stream) {
    const float* hidden  = (const float*)d_in[0];
    const float* routing = (const float*)d_in[1];
    const float* w1      = (const float*)d_in[2];
    const float* w2      = (const float*)d_in[3];
    float* out = (float*)d_out;

    char* ws = (char*)d_ws;
    int*    cnt  = (int*)ws;
    int*    tok  = (int*)(ws + 64);
    float*  scal = (float*)(ws + 64 + 4096);
    __bf16* abuf = (__bf16*)(ws + 16384);
    __bf16* act  = (__bf16*)(ws + 16384 + (size_t)2 * 1024 * 1024);

    hipMemsetAsync(d_out, 0, (size_t)out_size * sizeof(float), stream);

    route_kernel<<<1, 128, 0, stream>>>(routing, cnt, tok, scal);
    prep_kernel<<<N_EXP * T_TOK, 64, 0, stream>>>(hidden, cnt, tok, abuf);
    gemm1_kernel<<<N_EXP * 64 * 4, 256, 0, stream>>>(w1, cnt, abuf, act);
    gemm2_kernel<<<N_EXP * 16 * KSPLIT * 4, 256, 0, stream>>>(w2, cnt, tok, scal, act, out);
}